// Round 1
// baseline (140.596 us; speedup 1.0000x reference)
//
#include <hip/hip_runtime.h>
#include <hip/hip_bf16.h>
#include <math.h>

#define DD 256
#define BB 8
#define TT 1024
#define MM (BB*TT)
#define NH 4
#define DKH 64
#define NQ 3

typedef __attribute__((ext_vector_type(8))) short bf16x8;
typedef __attribute__((ext_vector_type(4))) float f32x4;
typedef unsigned short u16;
typedef unsigned int u32;

__device__ __forceinline__ float bf2f(u16 u) {
  return __uint_as_float(((u32)u) << 16);
}
__device__ __forceinline__ u16 f2bf(float x) {
  __hip_bfloat16 h = __float2bfloat16(x);
  return *reinterpret_cast<u16*>(&h);
}
__device__ __forceinline__ uint2 pack4(float a, float b, float c, float d) {
  uint2 r;
  r.x = (u32)f2bf(a) | ((u32)f2bf(b) << 16);
  r.y = (u32)f2bf(c) | ((u32)f2bf(d) << 16);
  return r;
}

// ---------------------------------------------------------------------------
// Generic GEMM: out[M,256] = act(A[M,256] @ W[256,256]^T + bias), out bf16.
// Tile 64x64, BK=32, 4 waves (each wave a 32x32 quadrant of 2x2 MFMA frags).
// A is fp32 (converted during staging) or bf16. W always fp32.
// ---------------------------------------------------------------------------
template<bool ABF, int ACT>   // ACT: 0 = none, 1 = ELU
__global__ __launch_bounds__(256) void gemm64(const void* __restrict__ A_,
                                              const float* __restrict__ W,
                                              const float* __restrict__ bias,
                                              u16* __restrict__ out)
{
  __shared__ u16 As[64][40];   // padded stride 40 (80B, 16B-aligned rows)
  __shared__ u16 Bs[64][40];
  const int tid  = threadIdx.x;
  const int lane = tid & 63, wave = tid >> 6;
  const int wr = wave >> 1, wc = wave & 1;
  const int q  = lane >> 4, lr = lane & 15;
  const int m0 = blockIdx.x * 64, n0 = blockIdx.y * 64;
  const int rs = tid >> 3, cs = (tid & 7) * 4;

  f32x4 acc[2][2] = {};

  for (int k0 = 0; k0 < DD; k0 += 32) {
#pragma unroll
    for (int p = 0; p < 2; ++p) {
      const int rr = rs + p * 32;
      if constexpr (ABF) {
        const u16* Ap = (const u16*)A_ + (size_t)(m0 + rr) * DD + k0 + cs;
        *(uint2*)&As[rr][cs] = *(const uint2*)Ap;
      } else {
        const float4 v = *(const float4*)((const float*)A_ + (size_t)(m0 + rr) * DD + k0 + cs);
        *(uint2*)&As[rr][cs] = pack4(v.x, v.y, v.z, v.w);
      }
      const float4 wv = *(const float4*)(W + (size_t)(n0 + rr) * DD + k0 + cs);
      *(uint2*)&Bs[rr][cs] = pack4(wv.x, wv.y, wv.z, wv.w);
    }
    __syncthreads();
    const int koff = q * 8;
    bf16x8 av[2], bv[2];
#pragma unroll
    for (int i = 0; i < 2; ++i) av[i] = *(const bf16x8*)&As[wr * 32 + i * 16 + lr][koff];
#pragma unroll
    for (int j = 0; j < 2; ++j) bv[j] = *(const bf16x8*)&Bs[wc * 32 + j * 16 + lr][koff];
#pragma unroll
    for (int i = 0; i < 2; ++i)
#pragma unroll
      for (int j = 0; j < 2; ++j)
        acc[i][j] = __builtin_amdgcn_mfma_f32_16x16x32_bf16(av[i], bv[j], acc[i][j], 0, 0, 0);
    __syncthreads();
  }

#pragma unroll
  for (int i = 0; i < 2; ++i) {
#pragma unroll
    for (int j = 0; j < 2; ++j) {
      const int col = n0 + wc * 32 + j * 16 + lr;
      const float bvv = bias ? bias[col] : 0.f;
#pragma unroll
      for (int t = 0; t < 4; ++t) {
        const int row = m0 + wr * 32 + i * 16 + q * 4 + t;
        float v = acc[i][j][t] + bvv;
        if (ACT == 1) v = v > 0.f ? v : expm1f(v);
        out[(size_t)row * DD + col] = f2bf(v);
      }
    }
  }
}

// ---------------------------------------------------------------------------
// K3: gate = eta2 @ gw^T + gb; h = LN(x + sigmoid(gate)*eta2) fused.
// BM=32, BN=256 (full rows per block -> in-kernel LayerNorm).
// Writes h as bf16 everywhere + fp32 h_last for t == T-1 rows.
// ---------------------------------------------------------------------------
__global__ __launch_bounds__(256) void grn_gate_ln(
    const u16* __restrict__ eta2, const float* __restrict__ W,
    const float* __restrict__ gb, const float* __restrict__ x,
    const float* __restrict__ lng, const float* __restrict__ lnb,
    u16* __restrict__ hout, float* __restrict__ hlast)
{
  __shared__ u16 As[32][40];
  __shared__ u16 Bs[256][40];
  __shared__ float red_s[32][65];
  __shared__ float red_q[32][65];
  __shared__ float smean[32], srstd[32];

  const int tid  = threadIdx.x;
  const int lane = tid & 63, wave = tid >> 6;
  const int q  = lane >> 4, lr = lane & 15;
  const int m0 = blockIdx.x * 32;
  const int rs = tid >> 3, cs = (tid & 7) * 4;

  f32x4 acc[2][4] = {};

  for (int k0 = 0; k0 < DD; k0 += 32) {
    {
      const u16* Ap = eta2 + (size_t)(m0 + rs) * DD + k0 + cs;
      *(uint2*)&As[rs][cs] = *(const uint2*)Ap;
    }
#pragma unroll
    for (int p = 0; p < 8; ++p) {
      const int idx = tid + p * 256;
      const int rb = idx >> 3, cb = (idx & 7) * 4;
      const float4 wv = *(const float4*)(W + (size_t)rb * DD + k0 + cb);
      *(uint2*)&Bs[rb][cb] = pack4(wv.x, wv.y, wv.z, wv.w);
    }
    __syncthreads();
    const int koff = q * 8;
    bf16x8 av[2], bv[4];
#pragma unroll
    for (int i = 0; i < 2; ++i) av[i] = *(const bf16x8*)&As[i * 16 + lr][koff];
#pragma unroll
    for (int j = 0; j < 4; ++j) bv[j] = *(const bf16x8*)&Bs[wave * 64 + j * 16 + lr][koff];
#pragma unroll
    for (int i = 0; i < 2; ++i)
#pragma unroll
      for (int j = 0; j < 4; ++j)
        acc[i][j] = __builtin_amdgcn_mfma_f32_16x16x32_bf16(av[i], bv[j], acc[i][j], 0, 0, 0);
    __syncthreads();
  }

  // epilogue: gate -> sigmoid -> a = sig*eta2 -> pre = x + a
  float pre[2][4][4];
#pragma unroll
  for (int i = 0; i < 2; ++i) {
#pragma unroll
    for (int j = 0; j < 4; ++j) {
      const int n = wave * 64 + j * 16 + lr;
      const float gbn = gb[n];
#pragma unroll
      for (int t = 0; t < 4; ++t) {
        const int grow = m0 + i * 16 + q * 4 + t;
        const float gate = acc[i][j][t] + gbn;
        const float sig = 1.f / (1.f + expf(-gate));
        const float e2 = bf2f(eta2[(size_t)grow * DD + n]);
        pre[i][j][t] = x[(size_t)grow * DD + n] + sig * e2;
      }
    }
  }
  // row partial sums for LN
#pragma unroll
  for (int i = 0; i < 2; ++i) {
#pragma unroll
    for (int t = 0; t < 4; ++t) {
      float s = 0.f, sq = 0.f;
#pragma unroll
      for (int j = 0; j < 4; ++j) { const float v = pre[i][j][t]; s += v; sq += v * v; }
      const int ml = i * 16 + q * 4 + t;
      red_s[ml][wave * 16 + lr] = s;
      red_q[ml][wave * 16 + lr] = sq;
    }
  }
  __syncthreads();
  if (tid < 32) {
    float s = 0.f, sq = 0.f;
    for (int c2 = 0; c2 < 64; ++c2) { s += red_s[tid][c2]; sq += red_q[tid][c2]; }
    const float mean = s * (1.f / DD);
    const float var = sq * (1.f / DD) - mean * mean;
    smean[tid] = mean;
    srstd[tid] = rsqrtf(var + 1e-5f);
  }
  __syncthreads();
#pragma unroll
  for (int i = 0; i < 2; ++i) {
#pragma unroll
    for (int j = 0; j < 4; ++j) {
      const int n = wave * 64 + j * 16 + lr;
      const float gn = lng[n], bn = lnb[n];
#pragma unroll
      for (int t = 0; t < 4; ++t) {
        const int ml = i * 16 + q * 4 + t;
        const int grow = m0 + ml;
        const float hn = (pre[i][j][t] - smean[ml]) * srstd[ml] * gn + bn;
        hout[(size_t)grow * DD + n] = f2bf(hn);
        if ((grow & (TT - 1)) == (TT - 1))
          hlast[(size_t)(grow >> 10) * DD + n] = hn;
      }
    }
  }
}

// ---------------------------------------------------------------------------
// Tail: per-batch block. q, attention (last query row), out proj, LN, GRN2,
// quantile head. All fp32 except bf16 K/V reads.
// ---------------------------------------------------------------------------
__device__ __forceinline__ float dot256(const float* __restrict__ wrow, const float* vv) {
  float acc = 0.f;
#pragma unroll 8
  for (int k = 0; k < DD; k += 4) {
    const float4 w4 = *(const float4*)(wrow + k);
    acc += w4.x * vv[k] + w4.y * vv[k + 1] + w4.z * vv[k + 2] + w4.w * vv[k + 3];
  }
  return acc;
}

__device__ __forceinline__ float block_sum256(float v, float* scratch) {
  const int lane = threadIdx.x & 63, w = threadIdx.x >> 6;
#pragma unroll
  for (int off = 32; off; off >>= 1) v += __shfl_down(v, off);
  if (lane == 0) scratch[w] = v;
  __syncthreads();
  const float r = scratch[0] + scratch[1] + scratch[2] + scratch[3];
  __syncthreads();
  return r;
}

__global__ __launch_bounds__(256) void tail_kernel(
    const float* __restrict__ hlast, const u16* __restrict__ kbuf, const u16* __restrict__ vbuf,
    const float* __restrict__ wq, const float* __restrict__ wow, const float* __restrict__ wob,
    const float* __restrict__ alng, const float* __restrict__ alnb,
    const float* __restrict__ f1w, const float* __restrict__ f1b,
    const float* __restrict__ f2w, const float* __restrict__ f2b,
    const float* __restrict__ gw, const float* __restrict__ gbv,
    const float* __restrict__ lng, const float* __restrict__ lnb,
    const float* __restrict__ qhw, const float* __restrict__ qhb,
    float* __restrict__ out)
{
  __shared__ float hl[DD], bufA[DD], bufB[DD], bufC[DD];
  __shared__ float sc[NH][TT];
  __shared__ float red[8];
  const int b = blockIdx.x, tid = threadIdx.x;
  const int lane = tid & 63, w = tid >> 6;

  hl[tid] = hlast[(size_t)b * DD + tid];
  __syncthreads();
  bufA[tid] = dot256(wq + (size_t)tid * DD, hl);   // q (no bias)
  __syncthreads();

  // scores[h][s] = (q_h . k_h[s]) / 8
  for (int it = 0; it < 16; ++it) {
    const int idx = it * 256 + tid;
    const int hh = idx >> 10, s = idx & (TT - 1);
    const u16* kr = kbuf + ((size_t)(b * TT + s)) * DD + hh * DKH;
    float acc = 0.f;
#pragma unroll
    for (int d = 0; d < DKH; d += 8) {
      const bf16x8 kv = *(const bf16x8*)(kr + d);
#pragma unroll
      for (int e = 0; e < 8; ++e) acc += bf2f((u16)kv[e]) * bufA[hh * DKH + d + e];
    }
    sc[hh][s] = acc * 0.125f;
  }
  __syncthreads();

  // softmax: wave w handles head w
  {
    float* row = sc[w];
    float mx = -3.0e38f;
#pragma unroll
    for (int i = 0; i < 16; ++i) mx = fmaxf(mx, row[lane + 64 * i]);
#pragma unroll
    for (int off = 32; off; off >>= 1) mx = fmaxf(mx, __shfl_xor(mx, off));
    float ev[16]; float sum = 0.f;
#pragma unroll
    for (int i = 0; i < 16; ++i) { ev[i] = expf(row[lane + 64 * i] - mx); sum += ev[i]; }
#pragma unroll
    for (int off = 32; off; off >>= 1) sum += __shfl_xor(sum, off);
    const float inv = 1.f / sum;
#pragma unroll
    for (int i = 0; i < 16; ++i) row[lane + 64 * i] = ev[i] * inv;
  }
  __syncthreads();

  // ctx[n] = sum_s attn[h][s] * v[s][n]
  {
    const int hh = tid >> 6;
    const float* prow = sc[hh];
    const u16* vp = vbuf + (size_t)(b * TT) * DD + tid;
    float acc = 0.f;
    for (int s = 0; s < TT; s += 4) {
      const float4 p = *(const float4*)(prow + s);
      acc += p.x * bf2f(vp[(size_t)(s + 0) * DD]);
      acc += p.y * bf2f(vp[(size_t)(s + 1) * DD]);
      acc += p.z * bf2f(vp[(size_t)(s + 2) * DD]);
      acc += p.w * bf2f(vp[(size_t)(s + 3) * DD]);
    }
    bufB[tid] = acc;
  }
  __syncthreads();

  const float ao = dot256(wow + (size_t)tid * DD, bufB) + wob[tid];
  const float t2 = hl[tid] + ao;
  float s1 = block_sum256(t2, red);
  float s2 = block_sum256(t2 * t2, red);
  float mean = s1 * (1.f / DD), var = s2 * (1.f / DD) - mean * mean;
  const float h2 = (t2 - mean) * rsqrtf(var + 1e-5f) * alng[tid] + alnb[tid];
  bufA[tid] = h2;
  __syncthreads();

  float e1 = dot256(f1w + (size_t)tid * DD, bufA) + f1b[tid];
  e1 = e1 > 0.f ? e1 : expm1f(e1);
  bufB[tid] = e1;
  __syncthreads();
  const float e2 = dot256(f2w + (size_t)tid * DD, bufB) + f2b[tid];
  bufC[tid] = e2;
  __syncthreads();
  const float g = dot256(gw + (size_t)tid * DD, bufC) + gbv[tid];
  const float a = (1.f / (1.f + expf(-g))) * e2;
  const float pre = h2 + a;
  s1 = block_sum256(pre, red);
  s2 = block_sum256(pre * pre, red);
  mean = s1 * (1.f / DD); var = s2 * (1.f / DD) - mean * mean;
  const float h3 = (pre - mean) * rsqrtf(var + 1e-5f) * lng[tid] + lnb[tid];
  bufA[tid] = h3;
  __syncthreads();

  if (tid < NQ) {
    float acc = qhb[tid];
    const float* qr = qhw + (size_t)tid * DD;
    for (int k = 0; k < DD; ++k) acc += qr[k] * bufA[k];
    out[b * NQ + tid] = acc;
  }
}

// ---------------------------------------------------------------------------
extern "C" void kernel_launch(void* const* d_in, const int* in_sizes, int n_in,
                              void* d_out, int out_size, void* d_ws, size_t ws_size,
                              hipStream_t stream)
{
  const float* x       = (const float*)d_in[0];
  const float* g1_f1w  = (const float*)d_in[1];
  const float* g1_f1b  = (const float*)d_in[2];
  const float* g1_f2w  = (const float*)d_in[3];
  const float* g1_f2b  = (const float*)d_in[4];
  const float* g1_gw   = (const float*)d_in[5];
  const float* g1_gb   = (const float*)d_in[6];
  const float* g1_lng  = (const float*)d_in[7];
  const float* g1_lnb  = (const float*)d_in[8];
  const float* wq      = (const float*)d_in[9];
  const float* wk      = (const float*)d_in[10];
  const float* wv      = (const float*)d_in[11];
  const float* wo_w    = (const float*)d_in[12];
  const float* wo_b    = (const float*)d_in[13];
  const float* attn_lng= (const float*)d_in[14];
  const float* attn_lnb= (const float*)d_in[15];
  const float* g2_f1w  = (const float*)d_in[16];
  const float* g2_f1b  = (const float*)d_in[17];
  const float* g2_f2w  = (const float*)d_in[18];
  const float* g2_f2b  = (const float*)d_in[19];
  const float* g2_gw   = (const float*)d_in[20];
  const float* g2_gb   = (const float*)d_in[21];
  const float* g2_lng  = (const float*)d_in[22];
  const float* g2_lnb  = (const float*)d_in[23];
  const float* qh_w    = (const float*)d_in[24];
  const float* qh_b    = (const float*)d_in[25];
  float* out = (float*)d_out;

  char* w8 = (char*)d_ws;
  u16*  eta1  = (u16*)(w8);
  u16*  eta2  = (u16*)(w8 + ((size_t)4  << 20));
  u16*  hbuf  = (u16*)(w8 + ((size_t)8  << 20));
  u16*  kbuf  = (u16*)(w8 + ((size_t)12 << 20));
  u16*  vbuf  = (u16*)(w8 + ((size_t)16 << 20));
  float* hlast = (float*)(w8 + ((size_t)20 << 20));

  const dim3 blk(256);
  const dim3 g1(MM / 64, DD / 64);

  gemm64<false, 1><<<g1, blk, 0, stream>>>((const void*)x,    g1_f1w, g1_f1b, eta1);
  gemm64<true,  0><<<g1, blk, 0, stream>>>((const void*)eta1, g1_f2w, g1_f2b, eta2);
  grn_gate_ln<<<dim3(MM / 32), blk, 0, stream>>>(eta2, g1_gw, g1_gb, x, g1_lng, g1_lnb, hbuf, hlast);
  gemm64<true,  0><<<g1, blk, 0, stream>>>((const void*)hbuf, wk, nullptr, kbuf);
  gemm64<true,  0><<<g1, blk, 0, stream>>>((const void*)hbuf, wv, nullptr, vbuf);
  tail_kernel<<<dim3(BB), blk, 0, stream>>>(hlast, kbuf, vbuf, wq, wo_w, wo_b,
                                            attn_lng, attn_lnb,
                                            g2_f1w, g2_f1b, g2_f2w, g2_f2b,
                                            g2_gw, g2_gb, g2_lng, g2_lnb,
                                            qh_w, qh_b, out);
}

// Round 2
// 104.553 us; speedup vs baseline: 1.3447x; 1.3447x over previous
//
#include <hip/hip_runtime.h>
#include <hip/hip_bf16.h>
#include <math.h>

#define DD 256
#define BB 8
#define TT 1024
#define MM (BB*TT)
#define NH 4
#define DKH 64
#define NQ 3

typedef __attribute__((ext_vector_type(8))) short bf16x8;
typedef __attribute__((ext_vector_type(4))) float f32x4;
typedef unsigned short u16;
typedef unsigned int u32;

__device__ __forceinline__ float bf2f(u16 u) {
  return __uint_as_float(((u32)u) << 16);
}
__device__ __forceinline__ u16 f2bf(float x) {
  __hip_bfloat16 h = __float2bfloat16(x);
  return *reinterpret_cast<u16*>(&h);
}
__device__ __forceinline__ uint2 pack4(float a, float b, float c, float d) {
  uint2 r;
  r.x = (u32)f2bf(a) | ((u32)f2bf(b) << 16);
  r.y = (u32)f2bf(c) | ((u32)f2bf(d) << 16);
  return r;
}
__device__ __forceinline__ float wred(float v) {
#pragma unroll
  for (int off = 32; off; off >>= 1) v += __shfl_xor(v, off);
  return v;
}

// ---------------------------------------------------------------------------
// Generic GEMM: out[M,256] = act(A[M,256] @ W[256,256]^T + bias), out bf16.
// ---------------------------------------------------------------------------
template<bool ABF, int ACT>   // ACT: 0 = none, 1 = ELU
__global__ __launch_bounds__(256) void gemm64(const void* __restrict__ A_,
                                              const float* __restrict__ W,
                                              const float* __restrict__ bias,
                                              u16* __restrict__ out)
{
  __shared__ u16 As[64][40];
  __shared__ u16 Bs[64][40];
  const int tid  = threadIdx.x;
  const int lane = tid & 63, wave = tid >> 6;
  const int wr = wave >> 1, wc = wave & 1;
  const int q  = lane >> 4, lr = lane & 15;
  const int m0 = blockIdx.x * 64, n0 = blockIdx.y * 64;
  const int rs = tid >> 3, cs = (tid & 7) * 4;

  f32x4 acc[2][2] = {};

  for (int k0 = 0; k0 < DD; k0 += 32) {
#pragma unroll
    for (int p = 0; p < 2; ++p) {
      const int rr = rs + p * 32;
      if constexpr (ABF) {
        const u16* Ap = (const u16*)A_ + (size_t)(m0 + rr) * DD + k0 + cs;
        *(uint2*)&As[rr][cs] = *(const uint2*)Ap;
      } else {
        const float4 v = *(const float4*)((const float*)A_ + (size_t)(m0 + rr) * DD + k0 + cs);
        *(uint2*)&As[rr][cs] = pack4(v.x, v.y, v.z, v.w);
      }
      const float4 wv = *(const float4*)(W + (size_t)(n0 + rr) * DD + k0 + cs);
      *(uint2*)&Bs[rr][cs] = pack4(wv.x, wv.y, wv.z, wv.w);
    }
    __syncthreads();
    const int koff = q * 8;
    bf16x8 av[2], bv[2];
#pragma unroll
    for (int i = 0; i < 2; ++i) av[i] = *(const bf16x8*)&As[wr * 32 + i * 16 + lr][koff];
#pragma unroll
    for (int j = 0; j < 2; ++j) bv[j] = *(const bf16x8*)&Bs[wc * 32 + j * 16 + lr][koff];
#pragma unroll
    for (int i = 0; i < 2; ++i)
#pragma unroll
      for (int j = 0; j < 2; ++j)
        acc[i][j] = __builtin_amdgcn_mfma_f32_16x16x32_bf16(av[i], bv[j], acc[i][j], 0, 0, 0);
    __syncthreads();
  }

#pragma unroll
  for (int i = 0; i < 2; ++i) {
#pragma unroll
    for (int j = 0; j < 2; ++j) {
      const int col = n0 + wc * 32 + j * 16 + lr;
      const float bvv = bias ? bias[col] : 0.f;
#pragma unroll
      for (int t = 0; t < 4; ++t) {
        const int row = m0 + wr * 32 + i * 16 + q * 4 + t;
        float v = acc[i][j][t] + bvv;
        if (ACT == 1) v = v > 0.f ? v : expm1f(v);
        out[(size_t)row * DD + col] = f2bf(v);
      }
    }
  }
}

// ---------------------------------------------------------------------------
// Fused K/V projection: blockIdx.y in [0,8): 0-3 -> K cols, 4-7 -> V cols.
// ---------------------------------------------------------------------------
__global__ __launch_bounds__(256) void gemm_kv(const u16* __restrict__ A_,
                                               const float* __restrict__ Wk,
                                               const float* __restrict__ Wv,
                                               u16* __restrict__ kout,
                                               u16* __restrict__ vout)
{
  __shared__ u16 As[64][40];
  __shared__ u16 Bs[64][40];
  const int tid  = threadIdx.x;
  const int lane = tid & 63, wave = tid >> 6;
  const int wr = wave >> 1, wc = wave & 1;
  const int q  = lane >> 4, lr = lane & 15;
  const int ny = blockIdx.y;
  const float* W = (ny < 4) ? Wk : Wv;
  u16* out = (ny < 4) ? kout : vout;
  const int m0 = blockIdx.x * 64, n0 = (ny & 3) * 64;
  const int rs = tid >> 3, cs = (tid & 7) * 4;

  f32x4 acc[2][2] = {};

  for (int k0 = 0; k0 < DD; k0 += 32) {
#pragma unroll
    for (int p = 0; p < 2; ++p) {
      const int rr = rs + p * 32;
      const u16* Ap = A_ + (size_t)(m0 + rr) * DD + k0 + cs;
      *(uint2*)&As[rr][cs] = *(const uint2*)Ap;
      const float4 wv = *(const float4*)(W + (size_t)(n0 + rr) * DD + k0 + cs);
      *(uint2*)&Bs[rr][cs] = pack4(wv.x, wv.y, wv.z, wv.w);
    }
    __syncthreads();
    const int koff = q * 8;
    bf16x8 av[2], bv[2];
#pragma unroll
    for (int i = 0; i < 2; ++i) av[i] = *(const bf16x8*)&As[wr * 32 + i * 16 + lr][koff];
#pragma unroll
    for (int j = 0; j < 2; ++j) bv[j] = *(const bf16x8*)&Bs[wc * 32 + j * 16 + lr][koff];
#pragma unroll
    for (int i = 0; i < 2; ++i)
#pragma unroll
      for (int j = 0; j < 2; ++j)
        acc[i][j] = __builtin_amdgcn_mfma_f32_16x16x32_bf16(av[i], bv[j], acc[i][j], 0, 0, 0);
    __syncthreads();
  }

#pragma unroll
  for (int i = 0; i < 2; ++i) {
#pragma unroll
    for (int j = 0; j < 2; ++j) {
      const int col = n0 + wc * 32 + j * 16 + lr;
#pragma unroll
      for (int t = 0; t < 4; ++t) {
        const int row = m0 + wr * 32 + i * 16 + q * 4 + t;
        out[(size_t)row * DD + col] = f2bf(acc[i][j][t]);
      }
    }
  }
}

// ---------------------------------------------------------------------------
// K3: gate = eta2 @ gw^T + gb; h = LN(x + sigmoid(gate)*eta2) fused.
// ---------------------------------------------------------------------------
__global__ __launch_bounds__(256) void grn_gate_ln(
    const u16* __restrict__ eta2, const float* __restrict__ W,
    const float* __restrict__ gb, const float* __restrict__ x,
    const float* __restrict__ lng, const float* __restrict__ lnb,
    u16* __restrict__ hout, float* __restrict__ hlast)
{
  __shared__ u16 As[32][40];
  __shared__ u16 Bs[256][40];
  __shared__ float red_s[32][65];
  __shared__ float red_q[32][65];
  __shared__ float smean[32], srstd[32];

  const int tid  = threadIdx.x;
  const int lane = tid & 63, wave = tid >> 6;
  const int q  = lane >> 4, lr = lane & 15;
  const int m0 = blockIdx.x * 32;
  const int rs = tid >> 3, cs = (tid & 7) * 4;

  f32x4 acc[2][4] = {};

  for (int k0 = 0; k0 < DD; k0 += 32) {
    {
      const u16* Ap = eta2 + (size_t)(m0 + rs) * DD + k0 + cs;
      *(uint2*)&As[rs][cs] = *(const uint2*)Ap;
    }
#pragma unroll
    for (int p = 0; p < 8; ++p) {
      const int idx = tid + p * 256;
      const int rb = idx >> 3, cb = (idx & 7) * 4;
      const float4 wv = *(const float4*)(W + (size_t)rb * DD + k0 + cb);
      *(uint2*)&Bs[rb][cb] = pack4(wv.x, wv.y, wv.z, wv.w);
    }
    __syncthreads();
    const int koff = q * 8;
    bf16x8 av[2], bv[4];
#pragma unroll
    for (int i = 0; i < 2; ++i) av[i] = *(const bf16x8*)&As[i * 16 + lr][koff];
#pragma unroll
    for (int j = 0; j < 4; ++j) bv[j] = *(const bf16x8*)&Bs[wave * 64 + j * 16 + lr][koff];
#pragma unroll
    for (int i = 0; i < 2; ++i)
#pragma unroll
      for (int j = 0; j < 4; ++j)
        acc[i][j] = __builtin_amdgcn_mfma_f32_16x16x32_bf16(av[i], bv[j], acc[i][j], 0, 0, 0);
    __syncthreads();
  }

  float pre[2][4][4];
#pragma unroll
  for (int i = 0; i < 2; ++i) {
#pragma unroll
    for (int j = 0; j < 4; ++j) {
      const int n = wave * 64 + j * 16 + lr;
      const float gbn = gb[n];
#pragma unroll
      for (int t = 0; t < 4; ++t) {
        const int grow = m0 + i * 16 + q * 4 + t;
        const float gate = acc[i][j][t] + gbn;
        const float sig = 1.f / (1.f + expf(-gate));
        const float e2 = bf2f(eta2[(size_t)grow * DD + n]);
        pre[i][j][t] = x[(size_t)grow * DD + n] + sig * e2;
      }
    }
  }
#pragma unroll
  for (int i = 0; i < 2; ++i) {
#pragma unroll
    for (int t = 0; t < 4; ++t) {
      float s = 0.f, sq = 0.f;
#pragma unroll
      for (int j = 0; j < 4; ++j) { const float v = pre[i][j][t]; s += v; sq += v * v; }
      const int ml = i * 16 + q * 4 + t;
      red_s[ml][wave * 16 + lr] = s;
      red_q[ml][wave * 16 + lr] = sq;
    }
  }
  __syncthreads();
  if (tid < 32) {
    float s = 0.f, sq = 0.f;
    for (int c2 = 0; c2 < 64; ++c2) { s += red_s[tid][c2]; sq += red_q[tid][c2]; }
    const float mean = s * (1.f / DD);
    const float var = sq * (1.f / DD) - mean * mean;
    smean[tid] = mean;
    srstd[tid] = rsqrtf(var + 1e-5f);
  }
  __syncthreads();
#pragma unroll
  for (int i = 0; i < 2; ++i) {
#pragma unroll
    for (int j = 0; j < 4; ++j) {
      const int n = wave * 64 + j * 16 + lr;
      const float gn = lng[n], bn = lnb[n];
#pragma unroll
      for (int t = 0; t < 4; ++t) {
        const int ml = i * 16 + q * 4 + t;
        const int grow = m0 + ml;
        const float hn = (pre[i][j][t] - smean[ml]) * srstd[ml] * gn + bn;
        hout[(size_t)grow * DD + n] = f2bf(hn);
        if ((grow & (TT - 1)) == (TT - 1))
          hlast[(size_t)(grow >> 10) * DD + n] = hn;
      }
    }
  }
}

// ---------------------------------------------------------------------------
// Attention scores + softmax for the last query row. grid (NH, BB).
// probs[b][h][s] (fp32).
// ---------------------------------------------------------------------------
__global__ __launch_bounds__(256) void qk_softmax(
    const float* __restrict__ hlast, const u16* __restrict__ kbuf,
    const float* __restrict__ wq, float* __restrict__ probs)
{
  __shared__ float hl[DD], qh[DKH];
  __shared__ float red[8];
  const int h = blockIdx.x, b = blockIdx.y;
  const int tid = threadIdx.x, lane = tid & 63, w = tid >> 6;

  hl[tid] = hlast[(size_t)b * DD + tid];
  __syncthreads();
  {
    const int j = tid >> 2, seg = tid & 3;
    const float* wr = wq + (size_t)(h * DKH + j) * DD + seg * 64;
    const float* sp = hl + seg * 64;
    float acc = 0.f;
#pragma unroll
    for (int k = 0; k < 64; k += 4) {
      const float4 w4 = *(const float4*)(wr + k);
      acc += w4.x * sp[k] + w4.y * sp[k + 1] + w4.z * sp[k + 2] + w4.w * sp[k + 3];
    }
    acc += __shfl_xor(acc, 1);
    acc += __shfl_xor(acc, 2);
    if (seg == 0) qh[j] = acc;
  }
  __syncthreads();

  float sv[4], mx = -3.0e38f;
#pragma unroll
  for (int i = 0; i < 4; ++i) {
    const int s = tid + 256 * i;
    const u16* kr = kbuf + ((size_t)(b * TT + s)) * DD + h * DKH;
    float acc = 0.f;
#pragma unroll
    for (int d = 0; d < DKH; d += 8) {
      const bf16x8 kv = *(const bf16x8*)(kr + d);
#pragma unroll
      for (int e = 0; e < 8; ++e) acc += bf2f((u16)kv[e]) * qh[d + e];
    }
    sv[i] = acc * 0.125f;
    mx = fmaxf(mx, sv[i]);
  }
#pragma unroll
  for (int off = 32; off; off >>= 1) mx = fmaxf(mx, __shfl_xor(mx, off));
  if (lane == 0) red[w] = mx;
  __syncthreads();
  mx = fmaxf(fmaxf(red[0], red[1]), fmaxf(red[2], red[3]));
  float sum = 0.f;
#pragma unroll
  for (int i = 0; i < 4; ++i) { sv[i] = expf(sv[i] - mx); sum += sv[i]; }
  sum = wred(sum);
  if (lane == 0) red[4 + w] = sum;
  __syncthreads();
  const float inv = 1.f / (red[4] + red[5] + red[6] + red[7]);
  float* pp = probs + ((size_t)(b * NH + h)) * TT;
#pragma unroll
  for (int i = 0; i < 4; ++i) pp[tid + 256 * i] = sv[i] * inv;
}

// ---------------------------------------------------------------------------
// Tail: ctx + out-proj + LN + GRN2 + quantile head. grid(BB), 1024 threads.
// ctx s-split 8-way, matvecs k-split 4-way, everything LDS-reduced.
// ---------------------------------------------------------------------------
#define MV_PART(W, src) { \
  const int n_ = tid & 255, g_ = tid >> 8; \
  const float* wr_ = (W) + (size_t)n_ * DD + g_ * 64; \
  const float* sp_ = (src) + g_ * 64; \
  float acc_ = 0.f; \
  _Pragma("unroll") \
  for (int k_ = 0; k_ < 64; k_ += 4) { \
    const float4 w4_ = *(const float4*)(wr_ + k_); \
    acc_ += w4_.x * sp_[k_] + w4_.y * sp_[k_ + 1] + w4_.z * sp_[k_ + 2] + w4_.w * sp_[k_ + 3]; \
  } \
  part[g_][n_] = acc_; } \
  __syncthreads();

#define LN_STEP(val, gam, bet, dst) \
  __syncthreads(); \
  if (tid < DD) { part[4][tid] = (val); part[5][tid] = (val) * (val); } \
  __syncthreads(); \
  if (tid < 64) { \
    float s_ = 0.f, q_ = 0.f; \
    _Pragma("unroll") \
    for (int i_ = 0; i_ < 4; ++i_) { s_ += part[4][tid + 64 * i_]; q_ += part[5][tid + 64 * i_]; } \
    s_ = wred(s_); q_ = wred(q_); \
    if (tid == 0) { const float m_ = s_ * (1.f / DD); red2[0] = m_; red2[1] = rsqrtf(q_ * (1.f / DD) - m_ * m_ + 1e-5f); } \
  } \
  __syncthreads(); \
  if (tid < DD) dst[tid] = ((val) - red2[0]) * red2[1] * gam[tid] + bet[tid]; \
  __syncthreads();

__global__ __launch_bounds__(1024) void tail2(
    const float* __restrict__ hlast, const u16* __restrict__ vbuf,
    const float* __restrict__ probs,
    const float* __restrict__ wow, const float* __restrict__ wob,
    const float* __restrict__ alng, const float* __restrict__ alnb,
    const float* __restrict__ f1w, const float* __restrict__ f1b,
    const float* __restrict__ f2w, const float* __restrict__ f2b,
    const float* __restrict__ gw, const float* __restrict__ gbv,
    const float* __restrict__ lng, const float* __restrict__ lnb,
    const float* __restrict__ qhw, const float* __restrict__ qhb,
    float* __restrict__ out)
{
  __shared__ float pr[NH * TT];     // 16 KB
  __shared__ float part[8][DD];     // 8 KB
  __shared__ float hl[DD], bufA[DD], bufB[DD], bufC[DD];
  __shared__ float red2[2];
  const int b = blockIdx.x, tid = threadIdx.x;

#pragma unroll
  for (int i = 0; i < 4; ++i) pr[tid + 1024 * i] = probs[(size_t)b * NH * TT + tid + 1024 * i];
  if (tid < DD) hl[tid] = hlast[(size_t)b * DD + tid];
  __syncthreads();

  // ---- ctx: thread handles 2 consecutive n over a 128-wide s-slice
  {
    const int n = (tid & 127) * 2, g = tid >> 7;
    const int hh = n >> 6;
    const u16* vp = vbuf + ((size_t)(b * TT + g * 128)) * DD + n;
    const float* pp = pr + hh * TT + g * 128;
    float a0 = 0.f, a1 = 0.f;
    for (int s = 0; s < 128; ++s) {
      const u32 vv = *(const u32*)(vp + (size_t)s * DD);
      const float p = pp[s];
      a0 += p * bf2f((u16)(vv & 0xffffu));
      a1 += p * bf2f((u16)(vv >> 16));
    }
    part[g][n] = a0; part[g][n + 1] = a1;
  }
  __syncthreads();
  if (tid < DD) {
    float s = 0.f;
#pragma unroll
    for (int g = 0; g < 8; ++g) s += part[g][tid];
    bufB[tid] = s;          // ctx
  }
  __syncthreads();

  // ---- out proj + residual + LN -> bufA (h2)
  MV_PART(wow, bufB)
  float v = 0.f;
  if (tid < DD) v = hl[tid] + part[0][tid] + part[1][tid] + part[2][tid] + part[3][tid] + wob[tid];
  LN_STEP(v, alng, alnb, bufA)

  // ---- f1 + ELU -> bufB
  MV_PART(f1w, bufA)
  if (tid < DD) {
    float e1 = part[0][tid] + part[1][tid] + part[2][tid] + part[3][tid] + f1b[tid];
    bufB[tid] = e1 > 0.f ? e1 : expm1f(e1);
  }
  __syncthreads();

  // ---- f2 -> bufC (eta2)
  MV_PART(f2w, bufB)
  if (tid < DD) bufC[tid] = part[0][tid] + part[1][tid] + part[2][tid] + part[3][tid] + f2b[tid];
  __syncthreads();

  // ---- gate + residual + LN -> bufA (h3)
  MV_PART(gw, bufC)
  v = 0.f;
  if (tid < DD) {
    const float g = part[0][tid] + part[1][tid] + part[2][tid] + part[3][tid] + gbv[tid];
    v = bufA[tid] + (1.f / (1.f + expf(-g))) * bufC[tid];
  }
  LN_STEP(v, lng, lnb, bufA)

  // ---- quantile head
  if (tid < 64 * NQ) {
    const int qi = tid >> 6, lane = tid & 63;
    float acc = 0.f;
#pragma unroll
    for (int i = 0; i < 4; ++i) acc += qhw[(size_t)qi * DD + lane + 64 * i] * bufA[lane + 64 * i];
    acc = wred(acc);
    if (lane == 0) out[b * NQ + qi] = acc + qhb[qi];
  }
}

// ---------------------------------------------------------------------------
extern "C" void kernel_launch(void* const* d_in, const int* in_sizes, int n_in,
                              void* d_out, int out_size, void* d_ws, size_t ws_size,
                              hipStream_t stream)
{
  const float* x       = (const float*)d_in[0];
  const float* g1_f1w  = (const float*)d_in[1];
  const float* g1_f1b  = (const float*)d_in[2];
  const float* g1_f2w  = (const float*)d_in[3];
  const float* g1_f2b  = (const float*)d_in[4];
  const float* g1_gw   = (const float*)d_in[5];
  const float* g1_gb   = (const float*)d_in[6];
  const float* g1_lng  = (const float*)d_in[7];
  const float* g1_lnb  = (const float*)d_in[8];
  const float* wq      = (const float*)d_in[9];
  const float* wk      = (const float*)d_in[10];
  const float* wv      = (const float*)d_in[11];
  const float* wo_w    = (const float*)d_in[12];
  const float* wo_b    = (const float*)d_in[13];
  const float* attn_lng= (const float*)d_in[14];
  const float* attn_lnb= (const float*)d_in[15];
  const float* g2_f1w  = (const float*)d_in[16];
  const float* g2_f1b  = (const float*)d_in[17];
  const float* g2_f2w  = (const float*)d_in[18];
  const float* g2_f2b  = (const float*)d_in[19];
  const float* g2_gw   = (const float*)d_in[20];
  const float* g2_gb   = (const float*)d_in[21];
  const float* g2_lng  = (const float*)d_in[22];
  const float* g2_lnb  = (const float*)d_in[23];
  const float* qh_w    = (const float*)d_in[24];
  const float* qh_b    = (const float*)d_in[25];
  float* out = (float*)d_out;

  char* w8 = (char*)d_ws;
  u16*  eta1  = (u16*)(w8);
  u16*  eta2  = (u16*)(w8 + ((size_t)4  << 20));
  u16*  hbuf  = (u16*)(w8 + ((size_t)8  << 20));
  u16*  kbuf  = (u16*)(w8 + ((size_t)12 << 20));
  u16*  vbuf  = (u16*)(w8 + ((size_t)16 << 20));
  float* hlast = (float*)(w8 + ((size_t)20 << 20));
  float* probs = (float*)(w8 + ((size_t)20 << 20) + (64 << 10));

  const dim3 blk(256);
  const dim3 g1(MM / 64, DD / 64);

  gemm64<false, 1><<<g1, blk, 0, stream>>>((const void*)x,    g1_f1w, g1_f1b, eta1);
  gemm64<true,  0><<<g1, blk, 0, stream>>>((const void*)eta1, g1_f2w, g1_f2b, eta2);
  grn_gate_ln<<<dim3(MM / 32), blk, 0, stream>>>(eta2, g1_gw, g1_gb, x, g1_lng, g1_lnb, hbuf, hlast);
  gemm_kv<<<dim3(MM / 64, 8), blk, 0, stream>>>(hbuf, wk, wv, kbuf, vbuf);
  qk_softmax<<<dim3(NH, BB), blk, 0, stream>>>(hlast, kbuf, wq, probs);
  tail2<<<dim3(BB), dim3(1024), 0, stream>>>(hlast, vbuf, probs,
                                             wo_w, wo_b, attn_lng, attn_lnb,
                                             g2_f1w, g2_f1b, g2_f2w, g2_f2b,
                                             g2_gw, g2_gb, g2_lng, g2_lnb,
                                             qh_w, qh_b, out);
}

// Round 3
// 91.791 us; speedup vs baseline: 1.5317x; 1.1390x over previous
//
#include <hip/hip_runtime.h>
#include <hip/hip_bf16.h>
#include <math.h>

#define DD 256
#define BB 8
#define TT 1024
#define MM (BB*TT)
#define NH 4
#define DKH 64
#define NQ 3

typedef __attribute__((ext_vector_type(8))) short bf16x8;
typedef __attribute__((ext_vector_type(4))) float f32x4;
typedef unsigned short u16;
typedef unsigned int u32;

__device__ __forceinline__ float bf2f(u16 u) {
  return __uint_as_float(((u32)u) << 16);
}
__device__ __forceinline__ u16 f2bf(float x) {
  __hip_bfloat16 h = __float2bfloat16(x);
  return *reinterpret_cast<u16*>(&h);
}
__device__ __forceinline__ uint2 pack4(float a, float b, float c, float d) {
  uint2 r;
  r.x = (u32)f2bf(a) | ((u32)f2bf(b) << 16);
  r.y = (u32)f2bf(c) | ((u32)f2bf(d) << 16);
  return r;
}
__device__ __forceinline__ float wred(float v) {
#pragma unroll
  for (int off = 32; off; off >>= 1) v += __shfl_xor(v, off);
  return v;
}

// ---------------------------------------------------------------------------
// Single-stage GEMM: out[M,256] = act(A[M,256] @ W[256,256]^T + bias).
// Full K staged once (one barrier), then 32 MFMAs per wave.
// ---------------------------------------------------------------------------
template<bool ABF, int ACT>   // ACT: 0 = none, 1 = ELU
__global__ __launch_bounds__(256) void gemm64(const void* __restrict__ A_,
                                              const float* __restrict__ W,
                                              const float* __restrict__ bias,
                                              u16* __restrict__ out)
{
  __shared__ u16 As[64][264];
  __shared__ u16 Bs[64][264];
  const int tid  = threadIdx.x;
  const int lane = tid & 63, wave = tid >> 6;
  const int wr = wave >> 1, wc = wave & 1;
  const int q  = lane >> 4, lr = lane & 15;
  const int m0 = blockIdx.x * 64, n0 = blockIdx.y * 64;

#pragma unroll
  for (int p = 0; p < 8; ++p) {
    const int c = tid + p * 256;
    const int row = c >> 5, col = (c & 31) * 8;
    if constexpr (ABF) {
      *(uint4*)&As[row][col] = *(const uint4*)((const u16*)A_ + (size_t)(m0 + row) * DD + col);
    } else {
      const float* ap = (const float*)A_ + (size_t)(m0 + row) * DD + col;
      const float4 v0 = *(const float4*)ap, v1 = *(const float4*)(ap + 4);
      *(uint2*)&As[row][col]     = pack4(v0.x, v0.y, v0.z, v0.w);
      *(uint2*)&As[row][col + 4] = pack4(v1.x, v1.y, v1.z, v1.w);
    }
    const float* wp = W + (size_t)(n0 + row) * DD + col;
    const float4 w0 = *(const float4*)wp, w1 = *(const float4*)(wp + 4);
    *(uint2*)&Bs[row][col]     = pack4(w0.x, w0.y, w0.z, w0.w);
    *(uint2*)&Bs[row][col + 4] = pack4(w1.x, w1.y, w1.z, w1.w);
  }
  __syncthreads();

  f32x4 acc[2][2] = {};
#pragma unroll
  for (int kk = 0; kk < 8; ++kk) {
    const int koff = kk * 32 + q * 8;
    bf16x8 av[2], bv[2];
    av[0] = *(const bf16x8*)&As[wr * 32 + lr][koff];
    av[1] = *(const bf16x8*)&As[wr * 32 + 16 + lr][koff];
    bv[0] = *(const bf16x8*)&Bs[wc * 32 + lr][koff];
    bv[1] = *(const bf16x8*)&Bs[wc * 32 + 16 + lr][koff];
#pragma unroll
    for (int i = 0; i < 2; ++i)
#pragma unroll
      for (int j = 0; j < 2; ++j)
        acc[i][j] = __builtin_amdgcn_mfma_f32_16x16x32_bf16(av[i], bv[j], acc[i][j], 0, 0, 0);
  }

#pragma unroll
  for (int i = 0; i < 2; ++i) {
#pragma unroll
    for (int j = 0; j < 2; ++j) {
      const int col = n0 + wc * 32 + j * 16 + lr;
      const float bvv = bias ? bias[col] : 0.f;
#pragma unroll
      for (int t = 0; t < 4; ++t) {
        const int row = m0 + wr * 32 + i * 16 + q * 4 + t;
        float v = acc[i][j][t] + bvv;
        if (ACT == 1) v = v > 0.f ? v : expm1f(v);
        out[(size_t)row * DD + col] = f2bf(v);
      }
    }
  }
}

// ---------------------------------------------------------------------------
// Fused K/V projection, single-stage. blockIdx.y: 0-3 -> K, 4-7 -> V.
// ---------------------------------------------------------------------------
__global__ __launch_bounds__(256) void gemm_kv(const u16* __restrict__ A_,
                                               const float* __restrict__ Wk,
                                               const float* __restrict__ Wv,
                                               u16* __restrict__ kout,
                                               u16* __restrict__ vout)
{
  __shared__ u16 As[64][264];
  __shared__ u16 Bs[64][264];
  const int tid  = threadIdx.x;
  const int lane = tid & 63, wave = tid >> 6;
  const int wr = wave >> 1, wc = wave & 1;
  const int q  = lane >> 4, lr = lane & 15;
  const int ny = blockIdx.y;
  const float* W = (ny < 4) ? Wk : Wv;
  u16* out = (ny < 4) ? kout : vout;
  const int m0 = blockIdx.x * 64, n0 = (ny & 3) * 64;

#pragma unroll
  for (int p = 0; p < 8; ++p) {
    const int c = tid + p * 256;
    const int row = c >> 5, col = (c & 31) * 8;
    *(uint4*)&As[row][col] = *(const uint4*)(A_ + (size_t)(m0 + row) * DD + col);
    const float* wp = W + (size_t)(n0 + row) * DD + col;
    const float4 w0 = *(const float4*)wp, w1 = *(const float4*)(wp + 4);
    *(uint2*)&Bs[row][col]     = pack4(w0.x, w0.y, w0.z, w0.w);
    *(uint2*)&Bs[row][col + 4] = pack4(w1.x, w1.y, w1.z, w1.w);
  }
  __syncthreads();

  f32x4 acc[2][2] = {};
#pragma unroll
  for (int kk = 0; kk < 8; ++kk) {
    const int koff = kk * 32 + q * 8;
    bf16x8 av[2], bv[2];
    av[0] = *(const bf16x8*)&As[wr * 32 + lr][koff];
    av[1] = *(const bf16x8*)&As[wr * 32 + 16 + lr][koff];
    bv[0] = *(const bf16x8*)&Bs[wc * 32 + lr][koff];
    bv[1] = *(const bf16x8*)&Bs[wc * 32 + 16 + lr][koff];
#pragma unroll
    for (int i = 0; i < 2; ++i)
#pragma unroll
      for (int j = 0; j < 2; ++j)
        acc[i][j] = __builtin_amdgcn_mfma_f32_16x16x32_bf16(av[i], bv[j], acc[i][j], 0, 0, 0);
  }

#pragma unroll
  for (int i = 0; i < 2; ++i) {
#pragma unroll
    for (int j = 0; j < 2; ++j) {
      const int col = n0 + wc * 32 + j * 16 + lr;
#pragma unroll
      for (int t = 0; t < 4; ++t) {
        const int row = m0 + wr * 32 + i * 16 + q * 4 + t;
        out[(size_t)row * DD + col] = f2bf(acc[i][j][t]);
      }
    }
  }
}

// ---------------------------------------------------------------------------
// K3: gate = eta2 @ gw^T + gb; h = LN(x + sigmoid(gate)*eta2) fused.
// BK=128 (4 barriers), shuffle-based LN partials.
// ---------------------------------------------------------------------------
__global__ __launch_bounds__(256) void grn_gate_ln(
    const u16* __restrict__ eta2, const float* __restrict__ W,
    const float* __restrict__ gb, const float* __restrict__ x,
    const float* __restrict__ lng, const float* __restrict__ lnb,
    u16* __restrict__ hout, float* __restrict__ hlast)
{
  __shared__ u16 As[32][136];
  __shared__ u16 Bs[256][136];
  __shared__ float red_s[32][5];
  __shared__ float red_q[32][5];
  __shared__ float smean[32], srstd[32];

  const int tid  = threadIdx.x;
  const int lane = tid & 63, wave = tid >> 6;
  const int q  = lane >> 4, lr = lane & 15;
  const int m0 = blockIdx.x * 32;

  f32x4 acc[2][4] = {};

  for (int k0 = 0; k0 < DD; k0 += 128) {
#pragma unroll
    for (int p = 0; p < 2; ++p) {
      const int c = tid + p * 256;
      const int row = c >> 4, col = (c & 15) * 8;
      *(uint4*)&As[row][col] = *(const uint4*)(eta2 + (size_t)(m0 + row) * DD + k0 + col);
    }
#pragma unroll
    for (int p = 0; p < 16; ++p) {
      const int c = tid + p * 256;
      const int row = c >> 4, col = (c & 15) * 8;
      const float* wp = W + (size_t)row * DD + k0 + col;
      const float4 w0 = *(const float4*)wp, w1 = *(const float4*)(wp + 4);
      *(uint2*)&Bs[row][col]     = pack4(w0.x, w0.y, w0.z, w0.w);
      *(uint2*)&Bs[row][col + 4] = pack4(w1.x, w1.y, w1.z, w1.w);
    }
    __syncthreads();
#pragma unroll
    for (int kk = 0; kk < 4; ++kk) {
      const int koff = kk * 32 + q * 8;
      bf16x8 av[2], bv[4];
#pragma unroll
      for (int i = 0; i < 2; ++i) av[i] = *(const bf16x8*)&As[i * 16 + lr][koff];
#pragma unroll
      for (int j = 0; j < 4; ++j) bv[j] = *(const bf16x8*)&Bs[wave * 64 + j * 16 + lr][koff];
#pragma unroll
      for (int i = 0; i < 2; ++i)
#pragma unroll
        for (int j = 0; j < 4; ++j)
          acc[i][j] = __builtin_amdgcn_mfma_f32_16x16x32_bf16(av[i], bv[j], acc[i][j], 0, 0, 0);
    }
    __syncthreads();
  }

  float pre[2][4][4];
#pragma unroll
  for (int i = 0; i < 2; ++i) {
#pragma unroll
    for (int j = 0; j < 4; ++j) {
      const int n = wave * 64 + j * 16 + lr;
      const float gbn = gb[n];
#pragma unroll
      for (int t = 0; t < 4; ++t) {
        const int grow = m0 + i * 16 + q * 4 + t;
        const float gate = acc[i][j][t] + gbn;
        const float sig = 1.f / (1.f + expf(-gate));
        const float e2 = bf2f(eta2[(size_t)grow * DD + n]);
        pre[i][j][t] = x[(size_t)grow * DD + n] + sig * e2;
      }
    }
  }
  // LN partials: reduce over j (regs) then lr (shuffle), 4 waves via LDS
#pragma unroll
  for (int i = 0; i < 2; ++i) {
#pragma unroll
    for (int t = 0; t < 4; ++t) {
      float s = 0.f, sq = 0.f;
#pragma unroll
      for (int j = 0; j < 4; ++j) { const float v = pre[i][j][t]; s += v; sq += v * v; }
#pragma unroll
      for (int m = 1; m <= 8; m <<= 1) { s += __shfl_xor(s, m); sq += __shfl_xor(sq, m); }
      if (lr == 0) {
        const int ml = i * 16 + q * 4 + t;
        red_s[ml][wave] = s;
        red_q[ml][wave] = sq;
      }
    }
  }
  __syncthreads();
  if (tid < 32) {
    const float s  = red_s[tid][0] + red_s[tid][1] + red_s[tid][2] + red_s[tid][3];
    const float sq = red_q[tid][0] + red_q[tid][1] + red_q[tid][2] + red_q[tid][3];
    const float mean = s * (1.f / DD);
    const float var = sq * (1.f / DD) - mean * mean;
    smean[tid] = mean;
    srstd[tid] = rsqrtf(var + 1e-5f);
  }
  __syncthreads();
#pragma unroll
  for (int i = 0; i < 2; ++i) {
#pragma unroll
    for (int j = 0; j < 4; ++j) {
      const int n = wave * 64 + j * 16 + lr;
      const float gn = lng[n], bn = lnb[n];
#pragma unroll
      for (int t = 0; t < 4; ++t) {
        const int ml = i * 16 + q * 4 + t;
        const int grow = m0 + ml;
        const float hn = (pre[i][j][t] - smean[ml]) * srstd[ml] * gn + bn;
        hout[(size_t)grow * DD + n] = f2bf(hn);
        if ((grow & (TT - 1)) == (TT - 1))
          hlast[(size_t)(grow >> 10) * DD + n] = hn;
      }
    }
  }
}

// ---------------------------------------------------------------------------
// Attention: q, scores, softmax AND per-head ctx. grid (NH, BB).
// Writes ctx[b][h*64 .. h*64+63] (fp32).
// ---------------------------------------------------------------------------
__global__ __launch_bounds__(256) void qk_softmax_ctx(
    const float* __restrict__ hlast, const u16* __restrict__ kbuf,
    const u16* __restrict__ vbuf, const float* __restrict__ wq,
    float* __restrict__ ctxbuf)
{
  __shared__ float hl[DD], qh[DKH];
  __shared__ float red[8];
  __shared__ float pr[TT];
  __shared__ float part[8][DKH];
  const int h = blockIdx.x, b = blockIdx.y;
  const int tid = threadIdx.x, lane = tid & 63, w = tid >> 6;

  hl[tid] = hlast[(size_t)b * DD + tid];
  __syncthreads();
  {
    const int j = tid >> 2, seg = tid & 3;
    const float* wr = wq + (size_t)(h * DKH + j) * DD + seg * 64;
    const float* sp = hl + seg * 64;
    float acc = 0.f;
#pragma unroll
    for (int k = 0; k < 64; k += 4) {
      const float4 w4 = *(const float4*)(wr + k);
      acc += w4.x * sp[k] + w4.y * sp[k + 1] + w4.z * sp[k + 2] + w4.w * sp[k + 3];
    }
    acc += __shfl_xor(acc, 1);
    acc += __shfl_xor(acc, 2);
    if (seg == 0) qh[j] = acc;
  }
  __syncthreads();

  float sv[4], mx = -3.0e38f;
#pragma unroll
  for (int i = 0; i < 4; ++i) {
    const int s = tid + 256 * i;
    const u16* kr = kbuf + ((size_t)(b * TT + s)) * DD + h * DKH;
    float acc = 0.f;
#pragma unroll
    for (int d = 0; d < DKH; d += 8) {
      const bf16x8 kv = *(const bf16x8*)(kr + d);
#pragma unroll
      for (int e = 0; e < 8; ++e) acc += bf2f((u16)kv[e]) * qh[d + e];
    }
    sv[i] = acc * 0.125f;
    mx = fmaxf(mx, sv[i]);
  }
#pragma unroll
  for (int off = 32; off; off >>= 1) mx = fmaxf(mx, __shfl_xor(mx, off));
  if (lane == 0) red[w] = mx;
  __syncthreads();
  mx = fmaxf(fmaxf(red[0], red[1]), fmaxf(red[2], red[3]));
  float sum = 0.f;
#pragma unroll
  for (int i = 0; i < 4; ++i) { sv[i] = expf(sv[i] - mx); sum += sv[i]; }
  sum = wred(sum);
  if (lane == 0) red[4 + w] = sum;
  __syncthreads();
  const float inv = 1.f / (red[4] + red[5] + red[6] + red[7]);
#pragma unroll
  for (int i = 0; i < 4; ++i) pr[tid + 256 * i] = sv[i] * inv;
  __syncthreads();

  // ctx over this head's 64-wide V slice; 8 s-groups of 128
  {
    const int np = (tid & 31) * 2, sg = tid >> 5;
    const u16* vp = vbuf + ((size_t)(b * TT + sg * 128)) * DD + h * DKH + np;
    const float* pp = pr + sg * 128;
    float a0 = 0.f, a1 = 0.f;
    for (int s = 0; s < 128; ++s) {
      const u32 vv = *(const u32*)(vp + (size_t)s * DD);
      const float p = pp[s];
      a0 += p * bf2f((u16)(vv & 0xffffu));
      a1 += p * bf2f((u16)(vv >> 16));
    }
    part[sg][np] = a0; part[sg][np + 1] = a1;
  }
  __syncthreads();
  if (tid < DKH) {
    float s = 0.f;
#pragma unroll
    for (int g = 0; g < 8; ++g) s += part[g][tid];
    ctxbuf[(size_t)b * DD + h * DKH + tid] = s;
  }
}

// ---------------------------------------------------------------------------
// Tail: out-proj + LN + GRN2 + quantile head. grid(BB), 1024 threads.
// ---------------------------------------------------------------------------
#define MV_PART(W, src) { \
  const int n_ = tid & 255, g_ = tid >> 8; \
  const float* wr_ = (W) + (size_t)n_ * DD + g_ * 64; \
  const float* sp_ = (src) + g_ * 64; \
  float acc_ = 0.f; \
  _Pragma("unroll") \
  for (int k_ = 0; k_ < 64; k_ += 4) { \
    const float4 w4_ = *(const float4*)(wr_ + k_); \
    acc_ += w4_.x * sp_[k_] + w4_.y * sp_[k_ + 1] + w4_.z * sp_[k_ + 2] + w4_.w * sp_[k_ + 3]; \
  } \
  part[g_][n_] = acc_; } \
  __syncthreads();

#define LN_STEP(val, gam, bet, dst) \
  __syncthreads(); \
  if (tid < DD) { part[4][tid] = (val); part[5][tid] = (val) * (val); } \
  __syncthreads(); \
  if (tid < 64) { \
    float s_ = 0.f, q_ = 0.f; \
    _Pragma("unroll") \
    for (int i_ = 0; i_ < 4; ++i_) { s_ += part[4][tid + 64 * i_]; q_ += part[5][tid + 64 * i_]; } \
    s_ = wred(s_); q_ = wred(q_); \
    if (tid == 0) { const float m_ = s_ * (1.f / DD); red2[0] = m_; red2[1] = rsqrtf(q_ * (1.f / DD) - m_ * m_ + 1e-5f); } \
  } \
  __syncthreads(); \
  if (tid < DD) dst[tid] = ((val) - red2[0]) * red2[1] * gam[tid] + bet[tid]; \
  __syncthreads();

__global__ __launch_bounds__(1024) void tail2(
    const float* __restrict__ hlast, const float* __restrict__ ctxbuf,
    const float* __restrict__ wow, const float* __restrict__ wob,
    const float* __restrict__ alng, const float* __restrict__ alnb,
    const float* __restrict__ f1w, const float* __restrict__ f1b,
    const float* __restrict__ f2w, const float* __restrict__ f2b,
    const float* __restrict__ gw, const float* __restrict__ gbv,
    const float* __restrict__ lng, const float* __restrict__ lnb,
    const float* __restrict__ qhw, const float* __restrict__ qhb,
    float* __restrict__ out)
{
  __shared__ float part[6][DD];
  __shared__ float hl[DD], bufA[DD], bufB[DD], bufC[DD];
  __shared__ float red2[2];
  const int b = blockIdx.x, tid = threadIdx.x;

  if (tid < DD) {
    hl[tid]   = hlast[(size_t)b * DD + tid];
    bufB[tid] = ctxbuf[(size_t)b * DD + tid];
  }
  __syncthreads();

  // ---- out proj + residual + LN -> bufA (h2)
  MV_PART(wow, bufB)
  float v = 0.f;
  if (tid < DD) v = hl[tid] + part[0][tid] + part[1][tid] + part[2][tid] + part[3][tid] + wob[tid];
  LN_STEP(v, alng, alnb, bufA)

  // ---- f1 + ELU -> bufB
  MV_PART(f1w, bufA)
  if (tid < DD) {
    float e1 = part[0][tid] + part[1][tid] + part[2][tid] + part[3][tid] + f1b[tid];
    bufB[tid] = e1 > 0.f ? e1 : expm1f(e1);
  }
  __syncthreads();

  // ---- f2 -> bufC (eta2)
  MV_PART(f2w, bufB)
  if (tid < DD) bufC[tid] = part[0][tid] + part[1][tid] + part[2][tid] + part[3][tid] + f2b[tid];
  __syncthreads();

  // ---- gate + residual + LN -> bufA (h3)
  MV_PART(gw, bufC)
  v = 0.f;
  if (tid < DD) {
    const float g = part[0][tid] + part[1][tid] + part[2][tid] + part[3][tid] + gbv[tid];
    v = bufA[tid] + (1.f / (1.f + expf(-g))) * bufC[tid];
  }
  LN_STEP(v, lng, lnb, bufA)

  // ---- quantile head
  if (tid < 64 * NQ) {
    const int qi = tid >> 6, lane = tid & 63;
    float acc = 0.f;
#pragma unroll
    for (int i = 0; i < 4; ++i) acc += qhw[(size_t)qi * DD + lane + 64 * i] * bufA[lane + 64 * i];
    acc = wred(acc);
    if (lane == 0) out[b * NQ + qi] = acc + qhb[qi];
  }
}

// ---------------------------------------------------------------------------
extern "C" void kernel_launch(void* const* d_in, const int* in_sizes, int n_in,
                              void* d_out, int out_size, void* d_ws, size_t ws_size,
                              hipStream_t stream)
{
  const float* x       = (const float*)d_in[0];
  const float* g1_f1w  = (const float*)d_in[1];
  const float* g1_f1b  = (const float*)d_in[2];
  const float* g1_f2w  = (const float*)d_in[3];
  const float* g1_f2b  = (const float*)d_in[4];
  const float* g1_gw   = (const float*)d_in[5];
  const float* g1_gb   = (const float*)d_in[6];
  const float* g1_lng  = (const float*)d_in[7];
  const float* g1_lnb  = (const float*)d_in[8];
  const float* wq      = (const float*)d_in[9];
  const float* wk      = (const float*)d_in[10];
  const float* wv      = (const float*)d_in[11];
  const float* wo_w    = (const float*)d_in[12];
  const float* wo_b    = (const float*)d_in[13];
  const float* attn_lng= (const float*)d_in[14];
  const float* attn_lnb= (const float*)d_in[15];
  const float* g2_f1w  = (const float*)d_in[16];
  const float* g2_f1b  = (const float*)d_in[17];
  const float* g2_f2w  = (const float*)d_in[18];
  const float* g2_f2b  = (const float*)d_in[19];
  const float* g2_gw   = (const float*)d_in[20];
  const float* g2_gb   = (const float*)d_in[21];
  const float* g2_lng  = (const float*)d_in[22];
  const float* g2_lnb  = (const float*)d_in[23];
  const float* qh_w    = (const float*)d_in[24];
  const float* qh_b    = (const float*)d_in[25];
  float* out = (float*)d_out;

  char* w8 = (char*)d_ws;
  u16*  eta1  = (u16*)(w8);
  u16*  eta2  = (u16*)(w8 + ((size_t)4  << 20));
  u16*  hbuf  = (u16*)(w8 + ((size_t)8  << 20));
  u16*  kbuf  = (u16*)(w8 + ((size_t)12 << 20));
  u16*  vbuf  = (u16*)(w8 + ((size_t)16 << 20));
  float* hlast = (float*)(w8 + ((size_t)20 << 20));
  float* ctxbuf = (float*)(w8 + ((size_t)20 << 20) + (64 << 10));

  const dim3 blk(256);
  const dim3 g1(MM / 64, DD / 64);

  gemm64<false, 1><<<g1, blk, 0, stream>>>((const void*)x,    g1_f1w, g1_f1b, eta1);
  gemm64<true,  0><<<g1, blk, 0, stream>>>((const void*)eta1, g1_f2w, g1_f2b, eta2);
  grn_gate_ln<<<dim3(MM / 32), blk, 0, stream>>>(eta2, g1_gw, g1_gb, x, g1_lng, g1_lnb, hbuf, hlast);
  gemm_kv<<<dim3(MM / 64, 8), blk, 0, stream>>>(hbuf, wk, wv, kbuf, vbuf);
  qk_softmax_ctx<<<dim3(NH, BB), blk, 0, stream>>>(hlast, kbuf, vbuf, wq, ctxbuf);
  tail2<<<dim3(BB), dim3(1024), 0, stream>>>(hlast, ctxbuf,
                                             wo_w, wo_b, attn_lng, attn_lnb,
                                             g2_f1w, g2_f1b, g2_f2w, g2_f2b,
                                             g2_gw, g2_gb, g2_lng, g2_lnb,
                                             qh_w, qh_b, out);
}

// Round 4
// 77.188 us; speedup vs baseline: 1.8215x; 1.1892x over previous
//
#include <hip/hip_runtime.h>
#include <hip/hip_bf16.h>
#include <math.h>

#define DD 256
#define BB 8
#define TT 1024
#define MM (BB*TT)
#define NH 4
#define DKH 64
#define NQ 3

typedef __attribute__((ext_vector_type(8))) short bf16x8;
typedef __attribute__((ext_vector_type(4))) float f32x4;
typedef unsigned short u16;
typedef unsigned int u32;

__device__ __forceinline__ float bf2f(u16 u) {
  return __uint_as_float(((u32)u) << 16);
}
__device__ __forceinline__ u16 f2bf(float x) {
  __hip_bfloat16 h = __float2bfloat16(x);
  return *reinterpret_cast<u16*>(&h);
}
__device__ __forceinline__ uint2 pack4(float a, float b, float c, float d) {
  uint2 r;
  r.x = (u32)f2bf(a) | ((u32)f2bf(b) << 16);
  r.y = (u32)f2bf(c) | ((u32)f2bf(d) << 16);
  return r;
}
__device__ __forceinline__ float wred(float v) {
#pragma unroll
  for (int off = 32; off; off >>= 1) v += __shfl_xor(v, off);
  return v;
}

// ---------------------------------------------------------------------------
// Single-stage GEMM: out[M,256] = act(A[M,256] @ W[256,256]^T + bias).
// ---------------------------------------------------------------------------
template<bool ABF, int ACT>   // ACT: 0 = none, 1 = ELU
__global__ __launch_bounds__(256) void gemm64(const void* __restrict__ A_,
                                              const float* __restrict__ W,
                                              const float* __restrict__ bias,
                                              u16* __restrict__ out)
{
  __shared__ u16 As[64][264];
  __shared__ u16 Bs[64][264];
  const int tid  = threadIdx.x;
  const int lane = tid & 63, wave = tid >> 6;
  const int wr = wave >> 1, wc = wave & 1;
  const int q  = lane >> 4, lr = lane & 15;
  const int m0 = blockIdx.x * 64, n0 = blockIdx.y * 64;

#pragma unroll
  for (int p = 0; p < 8; ++p) {
    const int c = tid + p * 256;
    const int row = c >> 5, col = (c & 31) * 8;
    if constexpr (ABF) {
      *(uint4*)&As[row][col] = *(const uint4*)((const u16*)A_ + (size_t)(m0 + row) * DD + col);
    } else {
      const float* ap = (const float*)A_ + (size_t)(m0 + row) * DD + col;
      const float4 v0 = *(const float4*)ap, v1 = *(const float4*)(ap + 4);
      *(uint2*)&As[row][col]     = pack4(v0.x, v0.y, v0.z, v0.w);
      *(uint2*)&As[row][col + 4] = pack4(v1.x, v1.y, v1.z, v1.w);
    }
    const float* wp = W + (size_t)(n0 + row) * DD + col;
    const float4 w0 = *(const float4*)wp, w1 = *(const float4*)(wp + 4);
    *(uint2*)&Bs[row][col]     = pack4(w0.x, w0.y, w0.z, w0.w);
    *(uint2*)&Bs[row][col + 4] = pack4(w1.x, w1.y, w1.z, w1.w);
  }
  __syncthreads();

  f32x4 acc[2][2] = {};
#pragma unroll
  for (int kk = 0; kk < 8; ++kk) {
    const int koff = kk * 32 + q * 8;
    bf16x8 av[2], bv[2];
    av[0] = *(const bf16x8*)&As[wr * 32 + lr][koff];
    av[1] = *(const bf16x8*)&As[wr * 32 + 16 + lr][koff];
    bv[0] = *(const bf16x8*)&Bs[wc * 32 + lr][koff];
    bv[1] = *(const bf16x8*)&Bs[wc * 32 + 16 + lr][koff];
#pragma unroll
    for (int i = 0; i < 2; ++i)
#pragma unroll
      for (int j = 0; j < 2; ++j)
        acc[i][j] = __builtin_amdgcn_mfma_f32_16x16x32_bf16(av[i], bv[j], acc[i][j], 0, 0, 0);
  }

#pragma unroll
  for (int i = 0; i < 2; ++i) {
#pragma unroll
    for (int j = 0; j < 2; ++j) {
      const int col = n0 + wc * 32 + j * 16 + lr;
      const float bvv = bias ? bias[col] : 0.f;
#pragma unroll
      for (int t = 0; t < 4; ++t) {
        const int row = m0 + wr * 32 + i * 16 + q * 4 + t;
        float v = acc[i][j][t] + bvv;
        if (ACT == 1) v = v > 0.f ? v : expm1f(v);
        out[(size_t)row * DD + col] = f2bf(v);
      }
    }
  }
}

// ---------------------------------------------------------------------------
// Fused K/V projection, single-stage. blockIdx.y: 0-3 -> K, 4-7 -> V.
// ---------------------------------------------------------------------------
__global__ __launch_bounds__(256) void gemm_kv(const u16* __restrict__ A_,
                                               const float* __restrict__ Wk,
                                               const float* __restrict__ Wv,
                                               u16* __restrict__ kout,
                                               u16* __restrict__ vout)
{
  __shared__ u16 As[64][264];
  __shared__ u16 Bs[64][264];
  const int tid  = threadIdx.x;
  const int lane = tid & 63, wave = tid >> 6;
  const int wr = wave >> 1, wc = wave & 1;
  const int q  = lane >> 4, lr = lane & 15;
  const int ny = blockIdx.y;
  const float* W = (ny < 4) ? Wk : Wv;
  u16* out = (ny < 4) ? kout : vout;
  const int m0 = blockIdx.x * 64, n0 = (ny & 3) * 64;

#pragma unroll
  for (int p = 0; p < 8; ++p) {
    const int c = tid + p * 256;
    const int row = c >> 5, col = (c & 31) * 8;
    *(uint4*)&As[row][col] = *(const uint4*)(A_ + (size_t)(m0 + row) * DD + col);
    const float* wp = W + (size_t)(n0 + row) * DD + col;
    const float4 w0 = *(const float4*)wp, w1 = *(const float4*)(wp + 4);
    *(uint2*)&Bs[row][col]     = pack4(w0.x, w0.y, w0.z, w0.w);
    *(uint2*)&Bs[row][col + 4] = pack4(w1.x, w1.y, w1.z, w1.w);
  }
  __syncthreads();

  f32x4 acc[2][2] = {};
#pragma unroll
  for (int kk = 0; kk < 8; ++kk) {
    const int koff = kk * 32 + q * 8;
    bf16x8 av[2], bv[2];
    av[0] = *(const bf16x8*)&As[wr * 32 + lr][koff];
    av[1] = *(const bf16x8*)&As[wr * 32 + 16 + lr][koff];
    bv[0] = *(const bf16x8*)&Bs[wc * 32 + lr][koff];
    bv[1] = *(const bf16x8*)&Bs[wc * 32 + 16 + lr][koff];
#pragma unroll
    for (int i = 0; i < 2; ++i)
#pragma unroll
      for (int j = 0; j < 2; ++j)
        acc[i][j] = __builtin_amdgcn_mfma_f32_16x16x32_bf16(av[i], bv[j], acc[i][j], 0, 0, 0);
  }

#pragma unroll
  for (int i = 0; i < 2; ++i) {
#pragma unroll
    for (int j = 0; j < 2; ++j) {
      const int col = n0 + wc * 32 + j * 16 + lr;
#pragma unroll
      for (int t = 0; t < 4; ++t) {
        const int row = m0 + wr * 32 + i * 16 + q * 4 + t;
        out[(size_t)row * DD + col] = f2bf(acc[i][j][t]);
      }
    }
  }
}

// ---------------------------------------------------------------------------
// K3: gate = eta2 @ gw^T + gb; h = LN(x + sigmoid(gate)*eta2) fused.
// ---------------------------------------------------------------------------
__global__ __launch_bounds__(256) void grn_gate_ln(
    const u16* __restrict__ eta2, const float* __restrict__ W,
    const float* __restrict__ gb, const float* __restrict__ x,
    const float* __restrict__ lng, const float* __restrict__ lnb,
    u16* __restrict__ hout, float* __restrict__ hlast)
{
  __shared__ u16 As[32][136];
  __shared__ u16 Bs[256][136];
  __shared__ float red_s[32][5];
  __shared__ float red_q[32][5];
  __shared__ float smean[32], srstd[32];

  const int tid  = threadIdx.x;
  const int lane = tid & 63, wave = tid >> 6;
  const int q  = lane >> 4, lr = lane & 15;
  const int m0 = blockIdx.x * 32;

  f32x4 acc[2][4] = {};

  for (int k0 = 0; k0 < DD; k0 += 128) {
#pragma unroll
    for (int p = 0; p < 2; ++p) {
      const int c = tid + p * 256;
      const int row = c >> 4, col = (c & 15) * 8;
      *(uint4*)&As[row][col] = *(const uint4*)(eta2 + (size_t)(m0 + row) * DD + k0 + col);
    }
#pragma unroll
    for (int p = 0; p < 16; ++p) {
      const int c = tid + p * 256;
      const int row = c >> 4, col = (c & 15) * 8;
      const float* wp = W + (size_t)row * DD + k0 + col;
      const float4 w0 = *(const float4*)wp, w1 = *(const float4*)(wp + 4);
      *(uint2*)&Bs[row][col]     = pack4(w0.x, w0.y, w0.z, w0.w);
      *(uint2*)&Bs[row][col + 4] = pack4(w1.x, w1.y, w1.z, w1.w);
    }
    __syncthreads();
#pragma unroll
    for (int kk = 0; kk < 4; ++kk) {
      const int koff = kk * 32 + q * 8;
      bf16x8 av[2], bv[4];
#pragma unroll
      for (int i = 0; i < 2; ++i) av[i] = *(const bf16x8*)&As[i * 16 + lr][koff];
#pragma unroll
      for (int j = 0; j < 4; ++j) bv[j] = *(const bf16x8*)&Bs[wave * 64 + j * 16 + lr][koff];
#pragma unroll
      for (int i = 0; i < 2; ++i)
#pragma unroll
        for (int j = 0; j < 4; ++j)
          acc[i][j] = __builtin_amdgcn_mfma_f32_16x16x32_bf16(av[i], bv[j], acc[i][j], 0, 0, 0);
    }
    __syncthreads();
  }

  float pre[2][4][4];
#pragma unroll
  for (int i = 0; i < 2; ++i) {
#pragma unroll
    for (int j = 0; j < 4; ++j) {
      const int n = wave * 64 + j * 16 + lr;
      const float gbn = gb[n];
#pragma unroll
      for (int t = 0; t < 4; ++t) {
        const int grow = m0 + i * 16 + q * 4 + t;
        const float gate = acc[i][j][t] + gbn;
        const float sig = 1.f / (1.f + expf(-gate));
        const float e2 = bf2f(eta2[(size_t)grow * DD + n]);
        pre[i][j][t] = x[(size_t)grow * DD + n] + sig * e2;
      }
    }
  }
#pragma unroll
  for (int i = 0; i < 2; ++i) {
#pragma unroll
    for (int t = 0; t < 4; ++t) {
      float s = 0.f, sq = 0.f;
#pragma unroll
      for (int j = 0; j < 4; ++j) { const float v = pre[i][j][t]; s += v; sq += v * v; }
#pragma unroll
      for (int m = 1; m <= 8; m <<= 1) { s += __shfl_xor(s, m); sq += __shfl_xor(sq, m); }
      if (lr == 0) {
        const int ml = i * 16 + q * 4 + t;
        red_s[ml][wave] = s;
        red_q[ml][wave] = sq;
      }
    }
  }
  __syncthreads();
  if (tid < 32) {
    const float s  = red_s[tid][0] + red_s[tid][1] + red_s[tid][2] + red_s[tid][3];
    const float sq = red_q[tid][0] + red_q[tid][1] + red_q[tid][2] + red_q[tid][3];
    const float mean = s * (1.f / DD);
    const float var = sq * (1.f / DD) - mean * mean;
    smean[tid] = mean;
    srstd[tid] = rsqrtf(var + 1e-5f);
  }
  __syncthreads();
#pragma unroll
  for (int i = 0; i < 2; ++i) {
#pragma unroll
    for (int j = 0; j < 4; ++j) {
      const int n = wave * 64 + j * 16 + lr;
      const float gn = lng[n], bn = lnb[n];
#pragma unroll
      for (int t = 0; t < 4; ++t) {
        const int ml = i * 16 + q * 4 + t;
        const int grow = m0 + ml;
        const float hn = (pre[i][j][t] - smean[ml]) * srstd[ml] * gn + bn;
        hout[(size_t)grow * DD + n] = f2bf(hn);
        if ((grow & (TT - 1)) == (TT - 1))
          hlast[(size_t)(grow >> 10) * DD + n] = hn;
      }
    }
  }
}

// ---------------------------------------------------------------------------
// Attention: q, scores, softmax, per-head ctx. grid (NH, BB).
// ALSO casts the 4 tail weight matrices (wow,f1w,f2w,gw) to bf16 into wbf
// (each of 32 blocks converts 8192 elements) — overlapped with attention.
// ---------------------------------------------------------------------------
__global__ __launch_bounds__(256) void qk_softmax_ctx(
    const float* __restrict__ hlast, const u16* __restrict__ kbuf,
    const u16* __restrict__ vbuf, const float* __restrict__ wq,
    const float* __restrict__ wow, const float* __restrict__ f1w,
    const float* __restrict__ f2w, const float* __restrict__ gw,
    u16* __restrict__ wbf, float* __restrict__ ctxbuf)
{
  __shared__ float hl[DD], qh[DKH];
  __shared__ float red[8];
  __shared__ float pr[TT];
  __shared__ float part[8][DKH];
  const int h = blockIdx.x, b = blockIdx.y;
  const int tid = threadIdx.x, lane = tid & 63, w = tid >> 6;

  // ---- weight cast (independent work; overlaps with the loads below)
  {
    const int bid = b * NH + h;               // 0..31
    const int mi = bid >> 3;                  // matrix index 0..3 (8 blocks each)
    const float* src = (mi == 0) ? wow : (mi == 1) ? f1w : (mi == 2) ? f2w : gw;
    const int off = (bid & 7) * 8192 + tid * 32;
    const float* sp = src + off;
    u16* dp = wbf + mi * 65536 + off;
#pragma unroll
    for (int i = 0; i < 32; i += 4) {
      const float4 v = *(const float4*)(sp + i);
      *(uint2*)(dp + i) = pack4(v.x, v.y, v.z, v.w);
    }
  }

  hl[tid] = hlast[(size_t)b * DD + tid];
  __syncthreads();
  {
    const int j = tid >> 2, seg = tid & 3;
    const float* wr = wq + (size_t)(h * DKH + j) * DD + seg * 64;
    const float* sp = hl + seg * 64;
    float acc = 0.f;
#pragma unroll
    for (int k = 0; k < 64; k += 4) {
      const float4 w4 = *(const float4*)(wr + k);
      acc += w4.x * sp[k] + w4.y * sp[k + 1] + w4.z * sp[k + 2] + w4.w * sp[k + 3];
    }
    acc += __shfl_xor(acc, 1);
    acc += __shfl_xor(acc, 2);
    if (seg == 0) qh[j] = acc;
  }
  __syncthreads();

  float sv[4], mx = -3.0e38f;
#pragma unroll
  for (int i = 0; i < 4; ++i) {
    const int s = tid + 256 * i;
    const u16* kr = kbuf + ((size_t)(b * TT + s)) * DD + h * DKH;
    float acc = 0.f;
#pragma unroll
    for (int d = 0; d < DKH; d += 8) {
      const bf16x8 kv = *(const bf16x8*)(kr + d);
#pragma unroll
      for (int e = 0; e < 8; ++e) acc += bf2f((u16)kv[e]) * qh[d + e];
    }
    sv[i] = acc * 0.125f;
    mx = fmaxf(mx, sv[i]);
  }
#pragma unroll
  for (int off = 32; off; off >>= 1) mx = fmaxf(mx, __shfl_xor(mx, off));
  if (lane == 0) red[w] = mx;
  __syncthreads();
  mx = fmaxf(fmaxf(red[0], red[1]), fmaxf(red[2], red[3]));
  float sum = 0.f;
#pragma unroll
  for (int i = 0; i < 4; ++i) { sv[i] = expf(sv[i] - mx); sum += sv[i]; }
  sum = wred(sum);
  if (lane == 0) red[4 + w] = sum;
  __syncthreads();
  const float inv = 1.f / (red[4] + red[5] + red[6] + red[7]);
#pragma unroll
  for (int i = 0; i < 4; ++i) pr[tid + 256 * i] = sv[i] * inv;
  __syncthreads();

  {
    const int np = (tid & 31) * 2, sg = tid >> 5;
    const u16* vp = vbuf + ((size_t)(b * TT + sg * 128)) * DD + h * DKH + np;
    const float* pp = pr + sg * 128;
    float a0 = 0.f, a1 = 0.f;
    for (int s = 0; s < 128; ++s) {
      const u32 vv = *(const u32*)(vp + (size_t)s * DD);
      const float p = pp[s];
      a0 += p * bf2f((u16)(vv & 0xffffu));
      a1 += p * bf2f((u16)(vv >> 16));
    }
    part[sg][np] = a0; part[sg][np + 1] = a1;
  }
  __syncthreads();
  if (tid < DKH) {
    float s = 0.f;
#pragma unroll
    for (int g = 0; g < 8; ++g) s += part[g][tid];
    ctxbuf[(size_t)b * DD + h * DKH + tid] = s;
  }
}

// ---------------------------------------------------------------------------
// Coalesced matvec: 16 waves x 16 rows; 32-lane halves own a row each iter.
// W16 is bf16 [256][256]; src/dst are LDS fp32 [256].
// ---------------------------------------------------------------------------
__device__ __forceinline__ void mv256b(const u16* __restrict__ W16,
                                       const float* __restrict__ srcbuf,
                                       float* __restrict__ dst,
                                       int wave, int lane)
{
  const int half = lane >> 5, l32 = lane & 31;
  float s[8];
  {
    const float4 s0 = *(const float4*)(srcbuf + l32 * 8);
    const float4 s1 = *(const float4*)(srcbuf + l32 * 8 + 4);
    s[0] = s0.x; s[1] = s0.y; s[2] = s0.z; s[3] = s0.w;
    s[4] = s1.x; s[5] = s1.y; s[6] = s1.z; s[7] = s1.w;
  }
#pragma unroll
  for (int i = 0; i < 8; ++i) {
    const int r = wave * 16 + i * 2 + half;
    const bf16x8 wv = *(const bf16x8*)(W16 + (size_t)r * DD + l32 * 8);
    float acc = 0.f;
#pragma unroll
    for (int e = 0; e < 8; ++e) acc += bf2f((u16)wv[e]) * s[e];
#pragma unroll
    for (int off = 16; off; off >>= 1) acc += __shfl_xor(acc, off);
    if (l32 == 0) dst[r] = acc;
  }
}

#define LN_STEP(val, gam, bet, dst) \
  __syncthreads(); \
  if (tid < DD) { lnS[tid] = (val); lnQ[tid] = (val) * (val); } \
  __syncthreads(); \
  if (tid < 64) { \
    float s_ = 0.f, q_ = 0.f; \
    _Pragma("unroll") \
    for (int i_ = 0; i_ < 4; ++i_) { s_ += lnS[tid + 64 * i_]; q_ += lnQ[tid + 64 * i_]; } \
    s_ = wred(s_); q_ = wred(q_); \
    if (tid == 0) { const float m_ = s_ * (1.f / DD); red2[0] = m_; red2[1] = rsqrtf(q_ * (1.f / DD) - m_ * m_ + 1e-5f); } \
  } \
  __syncthreads(); \
  if (tid < DD) dst[tid] = ((val) - red2[0]) * red2[1] * gam[tid] + bet[tid]; \
  __syncthreads();

// ---------------------------------------------------------------------------
// Tail: out-proj + LN + GRN2 + quantile head. grid(BB), 1024 threads.
// All 4 matvecs use coalesced bf16 weights from wbf.
// ---------------------------------------------------------------------------
__global__ __launch_bounds__(1024) void tail2(
    const float* __restrict__ hlast, const float* __restrict__ ctxbuf,
    const u16* __restrict__ wbf,
    const float* __restrict__ wob, const float* __restrict__ alng, const float* __restrict__ alnb,
    const float* __restrict__ f1b, const float* __restrict__ f2b,
    const float* __restrict__ gbv, const float* __restrict__ lng, const float* __restrict__ lnb,
    const float* __restrict__ qhw, const float* __restrict__ qhb,
    float* __restrict__ out)
{
  __shared__ float hl[DD], bufA[DD], bufB[DD], bufC[DD], part0[DD];
  __shared__ float lnS[DD], lnQ[DD];
  __shared__ float red2[2];
  const int b = blockIdx.x, tid = threadIdx.x;
  const int wave = tid >> 6, lane = tid & 63;

  if (tid < DD) {
    hl[tid]   = hlast[(size_t)b * DD + tid];
    bufB[tid] = ctxbuf[(size_t)b * DD + tid];
  }
  __syncthreads();

  // ---- out proj + residual + LN -> bufA (h2)
  mv256b(wbf + 0 * 65536, bufB, part0, wave, lane);
  __syncthreads();
  float v = 0.f;
  if (tid < DD) v = hl[tid] + part0[tid] + wob[tid];
  LN_STEP(v, alng, alnb, bufA)

  // ---- f1 + ELU -> bufB
  mv256b(wbf + 1 * 65536, bufA, part0, wave, lane);
  __syncthreads();
  if (tid < DD) {
    const float e1 = part0[tid] + f1b[tid];
    bufB[tid] = e1 > 0.f ? e1 : expm1f(e1);
  }
  __syncthreads();

  // ---- f2 -> bufC (eta2)
  mv256b(wbf + 2 * 65536, bufB, part0, wave, lane);
  __syncthreads();
  if (tid < DD) bufC[tid] = part0[tid] + f2b[tid];
  __syncthreads();

  // ---- gate + residual + LN -> bufA (h3)
  mv256b(wbf + 3 * 65536, bufC, part0, wave, lane);
  __syncthreads();
  v = 0.f;
  if (tid < DD) {
    const float g = part0[tid] + gbv[tid];
    v = bufA[tid] + (1.f / (1.f + expf(-g))) * bufC[tid];
  }
  LN_STEP(v, lng, lnb, bufA)

  // ---- quantile head
  if (tid < 64 * NQ) {
    const int qi = tid >> 6, l = tid & 63;
    float acc = 0.f;
#pragma unroll
    for (int i = 0; i < 4; ++i) acc += qhw[(size_t)qi * DD + l + 64 * i] * bufA[l + 64 * i];
    acc = wred(acc);
    if (l == 0) out[b * NQ + qi] = acc + qhb[qi];
  }
}

// ---------------------------------------------------------------------------
extern "C" void kernel_launch(void* const* d_in, const int* in_sizes, int n_in,
                              void* d_out, int out_size, void* d_ws, size_t ws_size,
                              hipStream_t stream)
{
  const float* x       = (const float*)d_in[0];
  const float* g1_f1w  = (const float*)d_in[1];
  const float* g1_f1b  = (const float*)d_in[2];
  const float* g1_f2w  = (const float*)d_in[3];
  const float* g1_f2b  = (const float*)d_in[4];
  const float* g1_gw   = (const float*)d_in[5];
  const float* g1_gb   = (const float*)d_in[6];
  const float* g1_lng  = (const float*)d_in[7];
  const float* g1_lnb  = (const float*)d_in[8];
  const float* wq      = (const float*)d_in[9];
  const float* wk      = (const float*)d_in[10];
  const float* wv      = (const float*)d_in[11];
  const float* wo_w    = (const float*)d_in[12];
  const float* wo_b    = (const float*)d_in[13];
  const float* attn_lng= (const float*)d_in[14];
  const float* attn_lnb= (const float*)d_in[15];
  const float* g2_f1w  = (const float*)d_in[16];
  const float* g2_f1b  = (const float*)d_in[17];
  const float* g2_f2w  = (const float*)d_in[18];
  const float* g2_f2b  = (const float*)d_in[19];
  const float* g2_gw   = (const float*)d_in[20];
  const float* g2_gb   = (const float*)d_in[21];
  const float* g2_lng  = (const float*)d_in[22];
  const float* g2_lnb  = (const float*)d_in[23];
  const float* qh_w    = (const float*)d_in[24];
  const float* qh_b    = (const float*)d_in[25];
  float* out = (float*)d_out;

  char* w8 = (char*)d_ws;
  u16*  eta1  = (u16*)(w8);                       // dead after gemm #2; reused as wbf
  u16*  wbf   = (u16*)(w8);                       // bf16 tail weights [4][256][256]
  u16*  eta2  = (u16*)(w8 + ((size_t)4  << 20));
  u16*  hbuf  = (u16*)(w8 + ((size_t)8  << 20));
  u16*  kbuf  = (u16*)(w8 + ((size_t)12 << 20));
  u16*  vbuf  = (u16*)(w8 + ((size_t)16 << 20));
  float* hlast = (float*)(w8 + ((size_t)20 << 20));
  float* ctxbuf = (float*)(w8 + ((size_t)20 << 20) + (64 << 10));

  const dim3 blk(256);
  const dim3 g1(MM / 64, DD / 64);

  gemm64<false, 1><<<g1, blk, 0, stream>>>((const void*)x,    g1_f1w, g1_f1b, eta1);
  gemm64<true,  0><<<g1, blk, 0, stream>>>((const void*)eta1, g1_f2w, g1_f2b, eta2);
  grn_gate_ln<<<dim3(MM / 32), blk, 0, stream>>>(eta2, g1_gw, g1_gb, x, g1_lng, g1_lnb, hbuf, hlast);
  gemm_kv<<<dim3(MM / 64, 8), blk, 0, stream>>>(hbuf, wk, wv, kbuf, vbuf);
  qk_softmax_ctx<<<dim3(NH, BB), blk, 0, stream>>>(hlast, kbuf, vbuf, wq,
                                                   wo_w, g2_f1w, g2_f2w, g2_gw,
                                                   wbf, ctxbuf);
  tail2<<<dim3(BB), dim3(1024), 0, stream>>>(hlast, ctxbuf, wbf,
                                             wo_b, attn_lng, attn_lnb,
                                             g2_f1b, g2_f2b, g2_gb, g2_lng, g2_lnb,
                                             qh_w, qh_b, out);
}